// Round 1
// baseline (4451.265 us; speedup 1.0000x reference)
//
#include <hip/hip_runtime.h>
#include <math.h>

#define D_MODEL 1024
#define N_TOK   8192
#define SEQ_L   1024
#define N_HEAD  16
#define HEAD_D  64
#define FF_DIM  4096

// ---------------------------------------------------------------------------
// LayerNorm: one block (256 thr) per token, D=1024 -> 4 elems/thread
// ---------------------------------------------------------------------------
__global__ __launch_bounds__(256) void ln_kernel(const float* __restrict__ x,
                                                 const float* __restrict__ g,
                                                 const float* __restrict__ b,
                                                 float* __restrict__ o)
{
    int t = blockIdx.x;
    const float* xr = x + (size_t)t * D_MODEL;
    float* orow = o + (size_t)t * D_MODEL;
    float vals[4];
    float lsum = 0.f, lsq = 0.f;
#pragma unroll
    for (int i = 0; i < 4; i++) {
        float v = xr[threadIdx.x + i * 256];
        vals[i] = v; lsum += v; lsq += v * v;
    }
#pragma unroll
    for (int off = 32; off > 0; off >>= 1) {
        lsum += __shfl_down(lsum, off);
        lsq  += __shfl_down(lsq,  off);
    }
    __shared__ float red[8];
    int wid = threadIdx.x >> 6, lane = threadIdx.x & 63;
    if (lane == 0) { red[wid] = lsum; red[4 + wid] = lsq; }
    __syncthreads();
    if (threadIdx.x == 0) {
        red[0] = red[0] + red[1] + red[2] + red[3];
        red[4] = red[4] + red[5] + red[6] + red[7];
    }
    __syncthreads();
    float mean = red[0] * (1.f / D_MODEL);
    float var  = red[4] * (1.f / D_MODEL) - mean * mean;
    float inv  = rsqrtf(var + 1e-5f);
#pragma unroll
    for (int i = 0; i < 4; i++) {
        int c = threadIdx.x + i * 256;
        orow[c] = (vals[i] - mean) * inv * g[c] + b[c];
    }
}

// ---------------------------------------------------------------------------
// Tiled fp32 GEMM:  C[M,N] (+)= act(A[M,K] @ W[K,N] + bias) (+ resid)
// 64x64 tile, BK=16, 256 threads, 4x4 microtile/thread.
// LDS rows padded to 68 floats (272 B = 16B-multiple) -> float4 LDS reads.
// act: 0 = none, 1 = quick_gelu. accum: C += result. bias/resid nullable.
// ---------------------------------------------------------------------------
#define BM 64
#define BN 64
#define BK 16

__global__ __launch_bounds__(256) void gemm_kernel(
    const float* __restrict__ A, int lda,
    const float* __restrict__ W, int ldw,
    const float* __restrict__ bias,
    const float* __restrict__ resid, int ldr,
    float* __restrict__ C, int ldc,
    int M, int N, int K, int act, int accum)
{
    __shared__ float sA[BK][BM + 4];
    __shared__ float sB[BK][BN + 4];

    int tid = threadIdx.x;
    int bm = blockIdx.y * BM;
    int bn = blockIdx.x * BN;

    int tm = (tid >> 4) << 2;   // 0..60, row group
    int tn = (tid & 15) << 2;   // 0..60, col group

    // A-tile load mapping: 64 rows x 16 k, one float4 per thread
    int am = tid >> 2;          // 0..63
    int ak = (tid & 3) << 2;    // 0,4,8,12
    // W-tile load mapping: 16 k x 64 n, one float4 per thread
    int wk = tid >> 4;          // 0..15
    int wn = (tid & 15) << 2;   // 0..60

    float acc[4][4];
#pragma unroll
    for (int i = 0; i < 4; i++)
#pragma unroll
        for (int j = 0; j < 4; j++) acc[i][j] = 0.f;

    for (int k0 = 0; k0 < K; k0 += BK) {
        float4 av = *(const float4*)&A[(size_t)(bm + am) * lda + k0 + ak];
        sA[ak + 0][am] = av.x;
        sA[ak + 1][am] = av.y;
        sA[ak + 2][am] = av.z;
        sA[ak + 3][am] = av.w;
        float4 wv = *(const float4*)&W[(size_t)(k0 + wk) * ldw + bn + wn];
        *(float4*)&sB[wk][wn] = wv;
        __syncthreads();
#pragma unroll
        for (int kk = 0; kk < BK; kk++) {
            float4 a4 = *(const float4*)&sA[kk][tm];
            float4 b4 = *(const float4*)&sB[kk][tn];
            float a[4] = {a4.x, a4.y, a4.z, a4.w};
            float b[4] = {b4.x, b4.y, b4.z, b4.w};
#pragma unroll
            for (int i = 0; i < 4; i++)
#pragma unroll
                for (int j = 0; j < 4; j++)
                    acc[i][j] += a[i] * b[j];
        }
        __syncthreads();
    }

#pragma unroll
    for (int i = 0; i < 4; i++) {
        int row = bm + tm + i;
#pragma unroll
        for (int j = 0; j < 4; j++) {
            int col = bn + tn + j;
            float c = acc[i][j];
            if (bias)  c += bias[col];
            if (act == 1) c = c * (1.f / (1.f + __expf(-1.702f * c)));  // quick_gelu
            if (resid) c += resid[(size_t)row * ldr + col];
            if (accum) c += C[(size_t)row * ldc + col];
            C[(size_t)row * ldc + col] = c;
        }
    }
}

// ---------------------------------------------------------------------------
// Flash-style attention, fp32. One block per (b, h, 64-row q-tile).
// 256 threads: thread owns one q-row r=tid/4 and 16 cols c0=(tid&3)*16.
// Online softmax (m,l per row shared across the row's 4 lanes via shuffles).
// ---------------------------------------------------------------------------
#define APAD 68

__global__ __launch_bounds__(256) void attn_kernel(
    const float* __restrict__ Q, const float* __restrict__ Km,
    const float* __restrict__ Vm, const int* __restrict__ mask,
    float* __restrict__ O)
{
    __shared__ float sQ[64][APAD];
    __shared__ float sK[64][APAD];
    __shared__ float sV[64][APAD];
    __shared__ float sP[64][APAD];
    __shared__ float sMb[64];

    int b  = blockIdx.z;
    int h  = blockIdx.y;
    int qt = blockIdx.x;
    int tid = threadIdx.x;
    int qbase = b * SEQ_L + qt * 64;
    const float scale = 0.125f;  // 1/sqrt(64)

    // load Q tile (scaled): 64x64 floats = 1024 float4, 4/thread
#pragma unroll
    for (int i = 0; i < 4; i++) {
        int idx = tid + i * 256;        // 0..1023
        int r = idx >> 4, c4 = (idx & 15) << 2;
        float4 qv = *(const float4*)&Q[(size_t)(qbase + r) * D_MODEL + h * HEAD_D + c4];
        qv.x *= scale; qv.y *= scale; qv.z *= scale; qv.w *= scale;
        *(float4*)&sQ[r][c4] = qv;
    }

    int r  = tid >> 2;          // q-row 0..63
    int c0 = (tid & 3) << 4;    // 16-col group

    float o[16];
#pragma unroll
    for (int j = 0; j < 16; j++) o[j] = 0.f;
    float mrun = -1e30f, lrun = 0.f;

    for (int kt = 0; kt < SEQ_L / 64; kt++) {
        __syncthreads();  // previous PV done reading sK/sV/sP
        int kbase = b * SEQ_L + kt * 64;
#pragma unroll
        for (int i = 0; i < 4; i++) {
            int idx = tid + i * 256;
            int rr = idx >> 4, c4 = (idx & 15) << 2;
            *(float4*)&sK[rr][c4] =
                *(const float4*)&Km[(size_t)(kbase + rr) * D_MODEL + h * HEAD_D + c4];
            *(float4*)&sV[rr][c4] =
                *(const float4*)&Vm[(size_t)(kbase + rr) * D_MODEL + h * HEAD_D + c4];
        }
        if (tid < 64) sMb[tid] = (mask[kbase + tid] > 0) ? 0.f : -1e30f;
        __syncthreads();

        // S = Q K^T for this thread's 16 keys
        float s[16];
#pragma unroll
        for (int j = 0; j < 16; j++) s[j] = 0.f;
        for (int d4 = 0; d4 < 16; d4++) {
            float4 qv = *(const float4*)&sQ[r][d4 << 2];
#pragma unroll
            for (int j = 0; j < 16; j++) {
                float4 kv = *(const float4*)&sK[c0 + j][d4 << 2];
                s[j] += qv.x * kv.x + qv.y * kv.y + qv.z * kv.z + qv.w * kv.w;
            }
        }
#pragma unroll
        for (int j = 0; j < 16; j++) s[j] += sMb[c0 + j];

        // row max across 16 local + 4 lanes
        float lm = -1e30f;
#pragma unroll
        for (int j = 0; j < 16; j++) lm = fmaxf(lm, s[j]);
        lm = fmaxf(lm, __shfl_xor(lm, 1));
        lm = fmaxf(lm, __shfl_xor(lm, 2));
        float mnew = fmaxf(mrun, lm);
        float alpha = __expf(mrun - mnew);

        float ls = 0.f;
#pragma unroll
        for (int j = 0; j < 16; j++) {
            float p = __expf(s[j] - mnew);
            sP[r][c0 + j] = p;
            ls += p;
        }
        ls += __shfl_xor(ls, 1);
        ls += __shfl_xor(ls, 2);
        lrun = lrun * alpha + ls;
        mrun = mnew;
#pragma unroll
        for (int j = 0; j < 16; j++) o[j] *= alpha;
        __syncthreads();  // sP fully written

        // O += P @ V  (this thread: row r, output dims c0..c0+15)
        for (int key = 0; key < 64; key++) {
            float p = sP[r][key];
            const float4* vrow = (const float4*)&sV[key][c0];
            float4 v0 = vrow[0], v1 = vrow[1], v2 = vrow[2], v3 = vrow[3];
            o[0]  += p * v0.x; o[1]  += p * v0.y; o[2]  += p * v0.z; o[3]  += p * v0.w;
            o[4]  += p * v1.x; o[5]  += p * v1.y; o[6]  += p * v1.z; o[7]  += p * v1.w;
            o[8]  += p * v2.x; o[9]  += p * v2.y; o[10] += p * v2.z; o[11] += p * v2.w;
            o[12] += p * v3.x; o[13] += p * v3.y; o[14] += p * v3.z; o[15] += p * v3.w;
        }
    }

    float inv = 1.f / lrun;
#pragma unroll
    for (int j = 0; j < 16; j++)
        O[(size_t)(qbase + r) * D_MODEL + h * HEAD_D + c0 + j] = o[j] * inv;
}

// ---------------------------------------------------------------------------
// Launch
// ---------------------------------------------------------------------------
extern "C" void kernel_launch(void* const* d_in, const int* in_sizes, int n_in,
                              void* d_out, int out_size, void* d_ws, size_t ws_size,
                              hipStream_t stream)
{
    const float* x     = (const float*)d_in[0];
    const int*   amask = (const int*)  d_in[1];
    const float* wq    = (const float*)d_in[2];
    const float* bq    = (const float*)d_in[3];
    const float* wk    = (const float*)d_in[4];
    const float* bk    = (const float*)d_in[5];
    const float* wv    = (const float*)d_in[6];
    const float* bv    = (const float*)d_in[7];
    const float* wo    = (const float*)d_in[8];
    const float* bo    = (const float*)d_in[9];
    const float* ln1s  = (const float*)d_in[10];
    const float* ln1b  = (const float*)d_in[11];
    const float* ln2s  = (const float*)d_in[12];
    const float* ln2b  = (const float*)d_in[13];
    const float* w1    = (const float*)d_in[14];
    const float* b1    = (const float*)d_in[15];
    const float* w2    = (const float*)d_in[16];
    const float* b2    = (const float*)d_in[17];
    float* out = (float*)d_out;

    const size_t SEG = (size_t)N_TOK * D_MODEL;  // 8M floats
    float* ws = (float*)d_ws;
    float* h  = ws;            // LN1 out, later attention out
    float* q  = ws + SEG;      // Q, later LN2 out
    float* k  = ws + 2 * SEG;  // K
    float* v  = ws + 3 * SEG;  // V

    // ff scratch: full 4096-wide pass if workspace allows, else 2048-wide
    // chunks aliasing the (dead-by-then) k/v segments. Deterministic per call.
    size_t avail = ws_size / sizeof(float);
    float* ff;
    int ffchunk;
    if (avail >= 4 * SEG + (size_t)N_TOK * FF_DIM) {
        ff = ws + 4 * SEG;
        ffchunk = FF_DIM;
    } else {
        ff = k;               // aliases k+v (16M floats) after attention
        ffchunk = 2048;
    }

    dim3 blk(256);

    // 1) h = LN1(x)
    ln_kernel<<<N_TOK, blk, 0, stream>>>(x, ln1s, ln1b, h);

    // 2) q/k/v = h @ W + b
    dim3 g1(D_MODEL / BN, N_TOK / BM);
    gemm_kernel<<<g1, blk, 0, stream>>>(h, D_MODEL, wq, D_MODEL, bq, nullptr, 0,
                                        q, D_MODEL, N_TOK, D_MODEL, D_MODEL, 0, 0);
    gemm_kernel<<<g1, blk, 0, stream>>>(h, D_MODEL, wk, D_MODEL, bk, nullptr, 0,
                                        k, D_MODEL, N_TOK, D_MODEL, D_MODEL, 0, 0);
    gemm_kernel<<<g1, blk, 0, stream>>>(h, D_MODEL, wv, D_MODEL, bv, nullptr, 0,
                                        v, D_MODEL, N_TOK, D_MODEL, D_MODEL, 0, 0);

    // 3) attention -> h (reused)
    dim3 ga(SEQ_L / 64, N_HEAD, 8);
    attn_kernel<<<ga, blk, 0, stream>>>(q, k, v, amask, h);

    // 4) out = x + attn @ wo + bo
    gemm_kernel<<<g1, blk, 0, stream>>>(h, D_MODEL, wo, D_MODEL, bo, x, D_MODEL,
                                        out, D_MODEL, N_TOK, D_MODEL, D_MODEL, 0, 0);

    // 5) q = LN2(out)
    ln_kernel<<<N_TOK, blk, 0, stream>>>(out, ln2s, ln2b, q);

    // 6) MLP: out += quick_gelu(q @ w1 + b1) @ w2 + b2, chunked over FF
    for (int c0 = 0; c0 < FF_DIM; c0 += ffchunk) {
        dim3 gf(ffchunk / BN, N_TOK / BM);
        gemm_kernel<<<gf, blk, 0, stream>>>(q, D_MODEL, w1 + c0, FF_DIM, b1 + c0,
                                            nullptr, 0, ff, ffchunk,
                                            N_TOK, ffchunk, D_MODEL, 1, 0);
        dim3 g2(D_MODEL / BN, N_TOK / BM);
        gemm_kernel<<<g2, blk, 0, stream>>>(ff, ffchunk, w2 + (size_t)c0 * D_MODEL,
                                            D_MODEL, (c0 == 0) ? b2 : nullptr,
                                            nullptr, 0, out, D_MODEL,
                                            N_TOK, D_MODEL, ffchunk, 0, 1);
    }
}

// Round 2
// 818.904 us; speedup vs baseline: 5.4356x; 5.4356x over previous
//
#include <hip/hip_runtime.h>
#include <math.h>

#define D_MODEL 1024
#define N_TOK   8192
#define SEQ_L   1024
#define N_HEAD  16
#define HEAD_D  64
#define FF_DIM  4096

typedef __attribute__((ext_vector_type(8))) short bf16x8;   // 8 bf16 = 4 VGPRs
typedef __attribute__((ext_vector_type(4))) float f32x4;

#define MFMA16(a, b, c) __builtin_amdgcn_mfma_f32_16x16x32_bf16((a), (b), (c), 0, 0, 0)

// async global->LDS, 16B per lane; LDS dest = wave-uniform base + lane*16
#define GLD16(gp, lp) __builtin_amdgcn_global_load_lds(                      \
    (const __attribute__((address_space(1))) void*)(gp),                     \
    (__attribute__((address_space(3))) void*)(lp), 16, 0, 0)

__device__ __forceinline__ short f2bf(float f) {   // fp32 -> bf16 (RNE)
    unsigned u = __float_as_uint(f);
    u += 0x7fffu + ((u >> 16) & 1u);
    return (short)(u >> 16);
}

// ---------------------------------------------------------------------------
// LayerNorm fp32 -> bf16. One block (256 thr) per token.
// ---------------------------------------------------------------------------
__global__ __launch_bounds__(256) void ln_kernel(const float* __restrict__ x,
                                                 const float* __restrict__ g,
                                                 const float* __restrict__ b,
                                                 short* __restrict__ o)
{
    int t = blockIdx.x;
    const float* xr = x + (size_t)t * D_MODEL;
    short* orow = o + (size_t)t * D_MODEL;
    float vals[4];
    float lsum = 0.f, lsq = 0.f;
#pragma unroll
    for (int i = 0; i < 4; i++) {
        float v = xr[threadIdx.x + i * 256];
        vals[i] = v; lsum += v; lsq += v * v;
    }
#pragma unroll
    for (int off = 32; off > 0; off >>= 1) {
        lsum += __shfl_down(lsum, off);
        lsq  += __shfl_down(lsq,  off);
    }
    __shared__ float red[8];
    int wid = threadIdx.x >> 6, lane = threadIdx.x & 63;
    if (lane == 0) { red[wid] = lsum; red[4 + wid] = lsq; }
    __syncthreads();
    if (threadIdx.x == 0) {
        red[0] = red[0] + red[1] + red[2] + red[3];
        red[4] = red[4] + red[5] + red[6] + red[7];
    }
    __syncthreads();
    float mean = red[0] * (1.f / D_MODEL);
    float var  = red[4] * (1.f / D_MODEL) - mean * mean;
    float inv  = rsqrtf(var + 1e-5f);
#pragma unroll
    for (int i = 0; i < 4; i++) {
        int c = threadIdx.x + i * 256;
        orow[c] = f2bf((vals[i] - mean) * inv * g[c] + b[c]);
    }
}

// ---------------------------------------------------------------------------
// Transpose + cast: src fp32 [R,C] -> dst bf16 [C,R]. 32x32 tiles.
// ---------------------------------------------------------------------------
__global__ __launch_bounds__(256) void transpose_cast(const float* __restrict__ src,
                                                      short* __restrict__ dst,
                                                      int R, int C)
{
    __shared__ float t[32][33];
    int r0 = blockIdx.y * 32, c0 = blockIdx.x * 32;
    int tid = threadIdx.x;
#pragma unroll
    for (int i = 0; i < 4; i++) {
        int idx = i * 256 + tid;
        int r = idx >> 5, c = idx & 31;
        t[r][c] = src[(size_t)(r0 + r) * C + c0 + c];
    }
    __syncthreads();
#pragma unroll
    for (int i = 0; i < 4; i++) {
        int idx = i * 256 + tid;
        int rr = idx >> 5, cc = idx & 31;
        dst[(size_t)(c0 + rr) * R + r0 + cc] = f2bf(t[cc][rr]);
    }
}

// ---------------------------------------------------------------------------
// V transpose (bf16): v [token][D] -> vt [(b*H+h)*64 + d][SEQ_L]
// ---------------------------------------------------------------------------
__global__ __launch_bounds__(256) void vt_kernel(const short* __restrict__ v,
                                                 short* __restrict__ vt)
{
    __shared__ short t[64][65];
    int lt = blockIdx.x, h = blockIdx.y, b = blockIdx.z;
    int tid = threadIdx.x;
#pragma unroll
    for (int i = 0; i < 16; i++) {
        int idx = i * 256 + tid;
        int l = idx >> 6, d = idx & 63;
        t[l][d] = v[(size_t)(b * SEQ_L + lt * 64 + l) * D_MODEL + h * 64 + d];
    }
    __syncthreads();
#pragma unroll
    for (int i = 0; i < 16; i++) {
        int idx = i * 256 + tid;
        int d = idx >> 6, l = idx & 63;
        vt[((size_t)(b * N_HEAD + h) * 64 + d) * SEQ_L + lt * 64 + l] = t[l][d];
    }
}

// ---------------------------------------------------------------------------
// bf16 MFMA GEMM (m97 structure): C[M,N] = epilogue(A[M,K] @ Bt[N,K]^T)
// 128x128 tile, BK=32, 256 thr = 4 waves, each wave 64x64 via 4x4 16x16 frags.
// A-frag: A[m=lane&15][k=quad*8+j]; B-frag: Bt[n=lane&15][k=quad*8+j];
// C/D: col=lane&15, row=quad*4+reg.
// epilogue: +bias (fp32), optional quick_gelu, optional fp32 resid add,
//           store fp32 (Cf) or bf16 (Cb).
// ---------------------------------------------------------------------------
__global__ __launch_bounds__(256) void gemm_bf16(
    const short* __restrict__ A, int lda,
    const short* __restrict__ Bt, int ldb,
    const float* __restrict__ bias,
    const float* __restrict__ resid,
    float* __restrict__ Cf, short* __restrict__ Cb,
    int ldc, int K, int act)
{
    __shared__ __align__(16) short sA[128 * 32];
    __shared__ __align__(16) short sB[128 * 32];
    const int tid = threadIdx.x;
    const int lane = tid & 63, wave = tid >> 6;
    const int quad = lane >> 4, l15 = lane & 15;
    const int bm = blockIdx.y * 128, bn = blockIdx.x * 128;
    const int wm = (wave >> 1) * 64, wn = (wave & 1) * 64;

    // staging: 8KB per tile = 512 x 16B chunks, 2 per thread per tile
    const int ca = tid, cb = tid + 256;
    const int ra = ca >> 2, ka = (ca & 3) << 3;
    const int rb = cb >> 2, kb = (cb & 3) << 3;

    f32x4 acc[4][4];
#pragma unroll
    for (int i = 0; i < 4; i++)
#pragma unroll
        for (int j = 0; j < 4; j++) acc[i][j] = (f32x4){0.f, 0.f, 0.f, 0.f};

    for (int k0 = 0; k0 < K; k0 += 32) {
        __syncthreads();
        GLD16(A  + (size_t)(bm + ra) * lda + k0 + ka, &sA[ca * 8]);
        GLD16(A  + (size_t)(bm + rb) * lda + k0 + kb, &sA[cb * 8]);
        GLD16(Bt + (size_t)(bn + ra) * ldb + k0 + ka, &sB[ca * 8]);
        GLD16(Bt + (size_t)(bn + rb) * ldb + k0 + kb, &sB[cb * 8]);
        __syncthreads();
        bf16x8 af[4], bfr[4];
#pragma unroll
        for (int mt = 0; mt < 4; mt++)
            af[mt] = *(const bf16x8*)&sA[(wm + mt * 16 + l15) * 32 + quad * 8];
#pragma unroll
        for (int nt = 0; nt < 4; nt++)
            bfr[nt] = *(const bf16x8*)&sB[(wn + nt * 16 + l15) * 32 + quad * 8];
#pragma unroll
        for (int mt = 0; mt < 4; mt++)
#pragma unroll
            for (int nt = 0; nt < 4; nt++)
                acc[mt][nt] = MFMA16(af[mt], bfr[nt], acc[mt][nt]);
    }

#pragma unroll
    for (int mt = 0; mt < 4; mt++)
#pragma unroll
        for (int nt = 0; nt < 4; nt++)
#pragma unroll
            for (int r = 0; r < 4; r++) {
                int row = bm + wm + mt * 16 + quad * 4 + r;
                int col = bn + wn + nt * 16 + l15;
                float v = acc[mt][nt][r] + bias[col];
                if (act) v = v / (1.f + __expf(-1.702f * v));   // quick_gelu
                if (resid) v += resid[(size_t)row * ldc + col];
                if (Cb) Cb[(size_t)row * ldc + col] = f2bf(v);
                else    Cf[(size_t)row * ldc + col] = v;
            }
}

// ---------------------------------------------------------------------------
// Flash attention, bf16 MFMA. Block = (qt, h, b): 64 q-rows, 4 waves,
// wave w owns q-rows w*16..w*16+15. Q/K frags straight from global
// (row-major [token][D] is exactly operand layout); V frags from Vt.
// P: fp32 softmax -> bf16 via per-wave LDS slab (C-layout -> A-layout).
// ---------------------------------------------------------------------------
__global__ __launch_bounds__(256) void attn_kernel(
    const short* __restrict__ Q, const short* __restrict__ Kb,
    const short* __restrict__ Vt, const int* __restrict__ mask,
    short* __restrict__ O)
{
    __shared__ float sMB[SEQ_L];
    __shared__ __align__(16) short sP[64 * 72];   // rows 144B (16B-mult)

    const int qt = blockIdx.x, h = blockIdx.y, b = blockIdx.z;
    const int tid = threadIdx.x;
    const int wave = tid >> 6, lane = tid & 63;
    const int quad = lane >> 4, l15 = lane & 15;

    for (int i = tid; i < SEQ_L; i += 256)
        sMB[i] = (mask[b * SEQ_L + i] > 0) ? 0.f : -1e30f;
    __syncthreads();

    const int qbase = b * SEQ_L + qt * 64;
    const short* qp = Q + (size_t)(qbase + wave * 16 + l15) * D_MODEL + h * HEAD_D + quad * 8;
    bf16x8 qf0 = *(const bf16x8*)qp;
    bf16x8 qf1 = *(const bf16x8*)(qp + 32);

    f32x4 o4[4];
#pragma unroll
    for (int nt = 0; nt < 4; nt++) o4[nt] = (f32x4){0.f, 0.f, 0.f, 0.f};
    float mrow[4] = {-1e30f, -1e30f, -1e30f, -1e30f};
    float lrow[4] = {0.f, 0.f, 0.f, 0.f};
    const size_t vpage = (size_t)(b * N_HEAD + h) * HEAD_D * SEQ_L;

    for (int kt = 0; kt < SEQ_L / 64; kt++) {
        const int kb = b * SEQ_L + kt * 64;
        f32x4 s[4];
#pragma unroll
        for (int nt = 0; nt < 4; nt++) s[nt] = (f32x4){0.f, 0.f, 0.f, 0.f};
#pragma unroll
        for (int nt = 0; nt < 4; nt++) {
            const short* kp = Kb + (size_t)(kb + nt * 16 + l15) * D_MODEL + h * HEAD_D + quad * 8;
            bf16x8 kf0 = *(const bf16x8*)kp;
            bf16x8 kf1 = *(const bf16x8*)(kp + 32);
            s[nt] = MFMA16(qf0, kf0, s[nt]);
            s[nt] = MFMA16(qf1, kf1, s[nt]);
        }
        // scale + mask (S C-layout: col=lane&15 -> key, row=quad*4+r -> q)
#pragma unroll
        for (int nt = 0; nt < 4; nt++) {
            float mbv = sMB[kt * 64 + nt * 16 + l15];
#pragma unroll
            for (int r = 0; r < 4; r++) s[nt][r] = s[nt][r] * 0.125f + mbv;
        }
        float alpha[4];
#pragma unroll
        for (int r = 0; r < 4; r++) {
            float lm = fmaxf(fmaxf(s[0][r], s[1][r]), fmaxf(s[2][r], s[3][r]));
            lm = fmaxf(lm, __shfl_xor(lm, 1));
            lm = fmaxf(lm, __shfl_xor(lm, 2));
            lm = fmaxf(lm, __shfl_xor(lm, 4));
            lm = fmaxf(lm, __shfl_xor(lm, 8));
            float mnew = fmaxf(mrow[r], lm);
            alpha[r] = __expf(mrow[r] - mnew);
            mrow[r] = mnew;
            float ls = 0.f;
#pragma unroll
            for (int nt = 0; nt < 4; nt++) {
                float p = __expf(s[nt][r] - mnew);
                ls += p;
                sP[(wave * 16 + quad * 4 + r) * 72 + nt * 16 + l15] = f2bf(p);
            }
            ls += __shfl_xor(ls, 1);
            ls += __shfl_xor(ls, 2);
            ls += __shfl_xor(ls, 4);
            ls += __shfl_xor(ls, 8);
            lrow[r] = lrow[r] * alpha[r] + ls;
        }
        __syncthreads();   // sP slab written (per-wave slab; conservative)
#pragma unroll
        for (int nt = 0; nt < 4; nt++)
#pragma unroll
            for (int r = 0; r < 4; r++) o4[nt][r] *= alpha[r];
        // P A-frag: m=lane&15 -> q row, k=quad*8+j -> key
        const short* pp = &sP[(wave * 16 + l15) * 72 + quad * 8];
        bf16x8 p0 = *(const bf16x8*)pp;
        bf16x8 p1 = *(const bf16x8*)(pp + 32);
#pragma unroll
        for (int nt = 0; nt < 4; nt++) {
            const short* vp = Vt + vpage + (size_t)(nt * 16 + l15) * SEQ_L + kt * 64 + quad * 8;
            bf16x8 vf0 = *(const bf16x8*)vp;
            bf16x8 vf1 = *(const bf16x8*)(vp + 32);
            o4[nt] = MFMA16(p0, vf0, o4[nt]);
            o4[nt] = MFMA16(p1, vf1, o4[nt]);
        }
        __syncthreads();   // all reads done before next kt overwrites sP
    }
#pragma unroll
    for (int r = 0; r < 4; r++) lrow[r] = 1.f / lrow[r];
#pragma unroll
    for (int nt = 0; nt < 4; nt++)
#pragma unroll
        for (int r = 0; r < 4; r++)
            O[(size_t)(qbase + wave * 16 + quad * 4 + r) * D_MODEL
              + h * HEAD_D + nt * 16 + l15] = f2bf(o4[nt][r] * lrow[r]);
}

// ---------------------------------------------------------------------------
// Launch
// ---------------------------------------------------------------------------
extern "C" void kernel_launch(void* const* d_in, const int* in_sizes, int n_in,
                              void* d_out, int out_size, void* d_ws, size_t ws_size,
                              hipStream_t stream)
{
    const float* x     = (const float*)d_in[0];
    const int*   amask = (const int*)  d_in[1];
    const float* wq    = (const float*)d_in[2];
    const float* bq    = (const float*)d_in[3];
    const float* wk    = (const float*)d_in[4];
    const float* bk    = (const float*)d_in[5];
    const float* wv    = (const float*)d_in[6];
    const float* bv    = (const float*)d_in[7];
    const float* wo    = (const float*)d_in[8];
    const float* bo    = (const float*)d_in[9];
    const float* ln1s  = (const float*)d_in[10];
    const float* ln1b  = (const float*)d_in[11];
    const float* ln2s  = (const float*)d_in[12];
    const float* ln2b  = (const float*)d_in[13];
    const float* w1    = (const float*)d_in[14];
    const float* b1    = (const float*)d_in[15];
    const float* w2    = (const float*)d_in[16];
    const float* b2    = (const float*)d_in[17];
    float* out = (float*)d_out;

    // workspace layout (bytes; peak 104 MB <= 128 MB proven available)
    char* w = (char*)d_ws;
    short* wqt = (short*)(w + (size_t)0);
    short* wkt = (short*)(w + ((size_t)2  << 20));
    short* wvt = (short*)(w + ((size_t)4  << 20));
    short* wot = (short*)(w + ((size_t)6  << 20));
    short* w1t = (short*)(w + ((size_t)8  << 20));
    short* w2t = (short*)(w + ((size_t)16 << 20));
    short* hb  = (short*)(w + ((size_t)24 << 20));   // LN1 out, later LN2 out
    short* qb  = (short*)(w + ((size_t)40 << 20));
    short* kbf = (short*)(w + ((size_t)56 << 20));
    short* vb  = (short*)(w + ((size_t)72 << 20));
    short* vtb = (short*)(w + ((size_t)88 << 20));
    short* attnb = vb;   // v dead after vt_kernel
    short* ffb   = qb;   // q/k/v/vt dead by MLP1 (64 MB span 40..104)

    dim3 blk(256);

    // weight prep: W [K,N] fp32 -> W^T [N,K] bf16
    transpose_cast<<<dim3(32, 32),  blk, 0, stream>>>(wq, wqt, 1024, 1024);
    transpose_cast<<<dim3(32, 32),  blk, 0, stream>>>(wk, wkt, 1024, 1024);
    transpose_cast<<<dim3(32, 32),  blk, 0, stream>>>(wv, wvt, 1024, 1024);
    transpose_cast<<<dim3(32, 32),  blk, 0, stream>>>(wo, wot, 1024, 1024);
    transpose_cast<<<dim3(128, 32), blk, 0, stream>>>(w1, w1t, 1024, 4096);
    transpose_cast<<<dim3(32, 128), blk, 0, stream>>>(w2, w2t, 4096, 1024);

    // 1) h = LN1(x) -> bf16
    ln_kernel<<<N_TOK, blk, 0, stream>>>(x, ln1s, ln1b, hb);

    // 2) q/k/v GEMMs (bf16 out)
    dim3 g1(D_MODEL / 128, N_TOK / 128);
    gemm_bf16<<<g1, blk, 0, stream>>>(hb, 1024, wqt, 1024, bq, nullptr,
                                      nullptr, qb, 1024, 1024, 0);
    gemm_bf16<<<g1, blk, 0, stream>>>(hb, 1024, wkt, 1024, bk, nullptr,
                                      nullptr, kbf, 1024, 1024, 0);
    gemm_bf16<<<g1, blk, 0, stream>>>(hb, 1024, wvt, 1024, bv, nullptr,
                                      nullptr, vb, 1024, 1024, 0);

    // 3) Vt, then flash attention -> attnb (bf16)
    vt_kernel<<<dim3(16, 16, 8), blk, 0, stream>>>(vb, vtb);
    attn_kernel<<<dim3(16, 16, 8), blk, 0, stream>>>(qb, kbf, vtb, amask, attnb);

    // 4) out = x + attn @ wo + bo  (fp32 out)
    gemm_bf16<<<g1, blk, 0, stream>>>(attnb, 1024, wot, 1024, bo, x,
                                      out, nullptr, 1024, 1024, 0);

    // 5) h = LN2(out) -> bf16
    ln_kernel<<<N_TOK, blk, 0, stream>>>(out, ln2s, ln2b, hb);

    // 6) MLP
    gemm_bf16<<<dim3(FF_DIM / 128, N_TOK / 128), blk, 0, stream>>>(
        hb, 1024, w1t, 1024, b1, nullptr, nullptr, ffb, 4096, 1024, 1);
    gemm_bf16<<<dim3(D_MODEL / 128, N_TOK / 128), blk, 0, stream>>>(
        ffb, 4096, w2t, 4096, b2, out, out, nullptr, 1024, 4096, 0);
}

// Round 3
// 788.924 us; speedup vs baseline: 5.6422x; 1.0380x over previous
//
#include <hip/hip_runtime.h>
#include <math.h>

#define D_MODEL 1024
#define N_TOK   8192
#define SEQ_L   1024
#define N_HEAD  16
#define HEAD_D  64
#define FF_DIM  4096

typedef __attribute__((ext_vector_type(8))) short bf16x8;   // 8 bf16 = 4 VGPRs
typedef __attribute__((ext_vector_type(4))) short short4v;
typedef __attribute__((ext_vector_type(4))) float f32x4;

#define MFMA16(a, b, c) __builtin_amdgcn_mfma_f32_16x16x32_bf16((a), (b), (c), 0, 0, 0)

// async global->LDS, 16B per lane; LDS dest = wave-uniform base + lane*16
#define GLD16(gp, lp) __builtin_amdgcn_global_load_lds(                      \
    (const __attribute__((address_space(1))) void*)(gp),                     \
    (__attribute__((address_space(3))) void*)(lp), 16, 0, 0)

__device__ __forceinline__ short f2bf(float f) {   // fp32 -> bf16 (RNE)
    unsigned u = __float_as_uint(f);
    u += 0x7fffu + ((u >> 16) & 1u);
    return (short)(u >> 16);
}

// ---------------------------------------------------------------------------
// LayerNorm fp32 -> bf16. One block (256 thr) per token.
// ---------------------------------------------------------------------------
__global__ __launch_bounds__(256) void ln_kernel(const float* __restrict__ x,
                                                 const float* __restrict__ g,
                                                 const float* __restrict__ b,
                                                 short* __restrict__ o)
{
    int t = blockIdx.x;
    const float* xr = x + (size_t)t * D_MODEL;
    short* orow = o + (size_t)t * D_MODEL;
    float vals[4];
    float lsum = 0.f, lsq = 0.f;
#pragma unroll
    for (int i = 0; i < 4; i++) {
        float v = xr[threadIdx.x + i * 256];
        vals[i] = v; lsum += v; lsq += v * v;
    }
#pragma unroll
    for (int off = 32; off > 0; off >>= 1) {
        lsum += __shfl_down(lsum, off);
        lsq  += __shfl_down(lsq,  off);
    }
    __shared__ float red[8];
    int wid = threadIdx.x >> 6, lane = threadIdx.x & 63;
    if (lane == 0) { red[wid] = lsum; red[4 + wid] = lsq; }
    __syncthreads();
    if (threadIdx.x == 0) {
        red[0] = red[0] + red[1] + red[2] + red[3];
        red[4] = red[4] + red[5] + red[6] + red[7];
    }
    __syncthreads();
    float mean = red[0] * (1.f / D_MODEL);
    float var  = red[4] * (1.f / D_MODEL) - mean * mean;
    float inv  = rsqrtf(var + 1e-5f);
#pragma unroll
    for (int i = 0; i < 4; i++) {
        int c = threadIdx.x + i * 256;
        orow[c] = f2bf((vals[i] - mean) * inv * g[c] + b[c]);
    }
}

// ---------------------------------------------------------------------------
// Transpose + cast: src fp32 [R,C] -> dst bf16 [C,R]. 32x32 tiles.
// ---------------------------------------------------------------------------
__global__ __launch_bounds__(256) void transpose_cast(const float* __restrict__ src,
                                                      short* __restrict__ dst,
                                                      int R, int C)
{
    __shared__ float t[32][33];
    int r0 = blockIdx.y * 32, c0 = blockIdx.x * 32;
    int tid = threadIdx.x;
#pragma unroll
    for (int i = 0; i < 4; i++) {
        int idx = i * 256 + tid;
        int r = idx >> 5, c = idx & 31;
        t[r][c] = src[(size_t)(r0 + r) * C + c0 + c];
    }
    __syncthreads();
#pragma unroll
    for (int i = 0; i < 4; i++) {
        int idx = i * 256 + tid;
        int rr = idx >> 5, cc = idx & 31;
        dst[(size_t)(c0 + rr) * R + r0 + cc] = f2bf(t[cc][rr]);
    }
}

// ---------------------------------------------------------------------------
// bf16 MFMA GEMM (m97 structure): C[M,N] = epilogue(A[M,K] @ Bt[N,K]^T)
// 128x128 tile, BK=32, 256 thr = 4 waves, each wave 64x64 via 4x4 16x16 frags.
// C/D layout: col=lane&15, row=quad*4+reg.
// Store modes: Cf (fp32), Cb (bf16), or Cvt (bf16 transposed to
// [(b*H+h)*64+d][SEQ_L] attention-V layout; lane's 4 rows are 4 consecutive
// seq positions -> one short4 store).
// ---------------------------------------------------------------------------
__global__ __launch_bounds__(256) void gemm_bf16(
    const short* __restrict__ A, int lda,
    const short* __restrict__ Bt, int ldb,
    const float* __restrict__ bias,
    const float* __restrict__ resid,
    float* __restrict__ Cf, short* __restrict__ Cb, short* __restrict__ Cvt,
    int ldc, int K, int act)
{
    __shared__ __align__(16) short sA[128 * 32];
    __shared__ __align__(16) short sB[128 * 32];
    const int tid = threadIdx.x;
    const int lane = tid & 63, wave = tid >> 6;
    const int quad = lane >> 4, l15 = lane & 15;
    const int bm = blockIdx.y * 128, bn = blockIdx.x * 128;
    const int wm = (wave >> 1) * 64, wn = (wave & 1) * 64;

    const int ca = tid, cb = tid + 256;
    const int ra = ca >> 2, ka = (ca & 3) << 3;
    const int rb = cb >> 2, kb = (cb & 3) << 3;

    f32x4 acc[4][4];
#pragma unroll
    for (int i = 0; i < 4; i++)
#pragma unroll
        for (int j = 0; j < 4; j++) acc[i][j] = (f32x4){0.f, 0.f, 0.f, 0.f};

    for (int k0 = 0; k0 < K; k0 += 32) {
        __syncthreads();
        GLD16(A  + (size_t)(bm + ra) * lda + k0 + ka, &sA[ca * 8]);
        GLD16(A  + (size_t)(bm + rb) * lda + k0 + kb, &sA[cb * 8]);
        GLD16(Bt + (size_t)(bn + ra) * ldb + k0 + ka, &sB[ca * 8]);
        GLD16(Bt + (size_t)(bn + rb) * ldb + k0 + kb, &sB[cb * 8]);
        __syncthreads();
        bf16x8 af[4], bfr[4];
#pragma unroll
        for (int mt = 0; mt < 4; mt++)
            af[mt] = *(const bf16x8*)&sA[(wm + mt * 16 + l15) * 32 + quad * 8];
#pragma unroll
        for (int nt = 0; nt < 4; nt++)
            bfr[nt] = *(const bf16x8*)&sB[(wn + nt * 16 + l15) * 32 + quad * 8];
#pragma unroll
        for (int mt = 0; mt < 4; mt++)
#pragma unroll
            for (int nt = 0; nt < 4; nt++)
                acc[mt][nt] = MFMA16(af[mt], bfr[nt], acc[mt][nt]);
    }

#pragma unroll
    for (int mt = 0; mt < 4; mt++)
#pragma unroll
        for (int nt = 0; nt < 4; nt++) {
            int row0 = bm + wm + mt * 16 + quad * 4;
            int col  = bn + wn + nt * 16 + l15;
            float vv[4];
#pragma unroll
            for (int r = 0; r < 4; r++) {
                float v = acc[mt][nt][r] + bias[col];
                if (act) v = v / (1.f + __expf(-1.702f * v));   // quick_gelu
                vv[r] = v;
            }
            if (Cvt) {
                // V layout: page = (b*16 + col>>6)*64 + (col&63), index l
                int bb = row0 >> 10, l0 = row0 & 1023;
                size_t page = (size_t)(bb * N_HEAD + (col >> 6)) * HEAD_D + (col & 63);
                short4v pk = { f2bf(vv[0]), f2bf(vv[1]), f2bf(vv[2]), f2bf(vv[3]) };
                *(short4v*)&Cvt[page * SEQ_L + l0] = pk;
            } else {
#pragma unroll
                for (int r = 0; r < 4; r++) {
                    int row = row0 + r;
                    float v = vv[r];
                    if (resid) v += resid[(size_t)row * ldc + col];
                    if (Cb) Cb[(size_t)row * ldc + col] = f2bf(v);
                    else    Cf[(size_t)row * ldc + col] = v;
                }
            }
        }
}

// ---------------------------------------------------------------------------
// Flash attention, bf16 MFMA. Block = (qt, h, b): 64 q-rows, 4 waves,
// wave w owns q-rows w*16..w*16+15. NO block barriers in the K-loop:
// the P slab is per-wave private, so in-wave lgkmcnt ordering suffices.
// All K+V frag loads issue at iteration top; V latency hides under softmax.
// ---------------------------------------------------------------------------
__global__ __launch_bounds__(256) void attn_kernel(
    const short* __restrict__ Q, const short* __restrict__ Kb,
    const short* __restrict__ Vt, const int* __restrict__ mask,
    short* __restrict__ O)
{
    __shared__ float sMB[SEQ_L];
    __shared__ __align__(16) short sP[64 * 72];   // rows 144B (16B-mult)

    const int qt = blockIdx.x, h = blockIdx.y, b = blockIdx.z;
    const int tid = threadIdx.x;
    const int wave = tid >> 6, lane = tid & 63;
    const int quad = lane >> 4, l15 = lane & 15;

    for (int i = tid; i < SEQ_L; i += 256)
        sMB[i] = (mask[b * SEQ_L + i] > 0) ? 0.f : -1e30f;
    __syncthreads();

    const int qbase = b * SEQ_L + qt * 64;
    const short* qp = Q + (size_t)(qbase + wave * 16 + l15) * D_MODEL + h * HEAD_D + quad * 8;
    bf16x8 qf0 = *(const bf16x8*)qp;
    bf16x8 qf1 = *(const bf16x8*)(qp + 32);

    f32x4 o4[4];
#pragma unroll
    for (int nt = 0; nt < 4; nt++) o4[nt] = (f32x4){0.f, 0.f, 0.f, 0.f};
    float mrow[4] = {-1e30f, -1e30f, -1e30f, -1e30f};
    float lrow[4] = {0.f, 0.f, 0.f, 0.f};
    const size_t vpage = (size_t)(b * N_HEAD + h) * HEAD_D * SEQ_L;
    short* pslab = &sP[wave * 16 * 72];   // per-wave private slab

#pragma unroll 4
    for (int kt = 0; kt < SEQ_L / 64; kt++) {
        const int kb = b * SEQ_L + kt * 64;
        // issue ALL K and V loads up front
        bf16x8 kf[4][2], vf[4][2];
#pragma unroll
        for (int nt = 0; nt < 4; nt++) {
            const short* kp = Kb + (size_t)(kb + nt * 16 + l15) * D_MODEL + h * HEAD_D + quad * 8;
            kf[nt][0] = *(const bf16x8*)kp;
            kf[nt][1] = *(const bf16x8*)(kp + 32);
            const short* vp = Vt + vpage + (size_t)(nt * 16 + l15) * SEQ_L + kt * 64 + quad * 8;
            vf[nt][0] = *(const bf16x8*)vp;
            vf[nt][1] = *(const bf16x8*)(vp + 32);
        }
        f32x4 s[4];
#pragma unroll
        for (int nt = 0; nt < 4; nt++) s[nt] = (f32x4){0.f, 0.f, 0.f, 0.f};
#pragma unroll
        for (int nt = 0; nt < 4; nt++) {
            s[nt] = MFMA16(qf0, kf[nt][0], s[nt]);
            s[nt] = MFMA16(qf1, kf[nt][1], s[nt]);
        }
        // scale + mask (S C-layout: col=lane&15 -> key, row=quad*4+r -> q)
#pragma unroll
        for (int nt = 0; nt < 4; nt++) {
            float mbv = sMB[kt * 64 + nt * 16 + l15];
#pragma unroll
            for (int r = 0; r < 4; r++) s[nt][r] = s[nt][r] * 0.125f + mbv;
        }
        float alpha[4];
#pragma unroll
        for (int r = 0; r < 4; r++) {
            float lm = fmaxf(fmaxf(s[0][r], s[1][r]), fmaxf(s[2][r], s[3][r]));
            lm = fmaxf(lm, __shfl_xor(lm, 1));
            lm = fmaxf(lm, __shfl_xor(lm, 2));
            lm = fmaxf(lm, __shfl_xor(lm, 4));
            lm = fmaxf(lm, __shfl_xor(lm, 8));
            float mnew = fmaxf(mrow[r], lm);
            alpha[r] = __expf(mrow[r] - mnew);
            mrow[r] = mnew;
            float ls = 0.f;
#pragma unroll
            for (int nt = 0; nt < 4; nt++) {
                float p = __expf(s[nt][r] - mnew);
                ls += p;
                pslab[(quad * 4 + r) * 72 + nt * 16 + l15] = f2bf(p);
            }
            ls += __shfl_xor(ls, 1);
            ls += __shfl_xor(ls, 2);
            ls += __shfl_xor(ls, 4);
            ls += __shfl_xor(ls, 8);
            lrow[r] = lrow[r] * alpha[r] + ls;
        }
#pragma unroll
        for (int nt = 0; nt < 4; nt++)
#pragma unroll
            for (int r = 0; r < 4; r++) o4[nt][r] *= alpha[r];
        // P A-frag: m=lane&15 -> q row, k=quad*8+j -> key (in-wave lgkm
        // ordering guarantees the slab writes above are visible)
        const short* pp = &pslab[l15 * 72 + quad * 8];
        bf16x8 p0 = *(const bf16x8*)pp;
        bf16x8 p1 = *(const bf16x8*)(pp + 32);
#pragma unroll
        for (int nt = 0; nt < 4; nt++) {
            o4[nt] = MFMA16(p0, vf[nt][0], o4[nt]);
            o4[nt] = MFMA16(p1, vf[nt][1], o4[nt]);
        }
    }
#pragma unroll
    for (int r = 0; r < 4; r++) lrow[r] = 1.f / lrow[r];
#pragma unroll
    for (int nt = 0; nt < 4; nt++)
#pragma unroll
        for (int r = 0; r < 4; r++)
            O[(size_t)(qbase + wave * 16 + quad * 4 + r) * D_MODEL
              + h * HEAD_D + nt * 16 + l15] = f2bf(o4[nt][r] * lrow[r]);
}

// ---------------------------------------------------------------------------
// Launch
// ---------------------------------------------------------------------------
extern "C" void kernel_launch(void* const* d_in, const int* in_sizes, int n_in,
                              void* d_out, int out_size, void* d_ws, size_t ws_size,
                              hipStream_t stream)
{
    const float* x     = (const float*)d_in[0];
    const int*   amask = (const int*)  d_in[1];
    const float* wq    = (const float*)d_in[2];
    const float* bq    = (const float*)d_in[3];
    const float* wk    = (const float*)d_in[4];
    const float* bk    = (const float*)d_in[5];
    const float* wv    = (const float*)d_in[6];
    const float* bv    = (const float*)d_in[7];
    const float* wo    = (const float*)d_in[8];
    const float* bo    = (const float*)d_in[9];
    const float* ln1s  = (const float*)d_in[10];
    const float* ln1b  = (const float*)d_in[11];
    const float* ln2s  = (const float*)d_in[12];
    const float* ln2b  = (const float*)d_in[13];
    const float* w1    = (const float*)d_in[14];
    const float* b1    = (const float*)d_in[15];
    const float* w2    = (const float*)d_in[16];
    const float* b2    = (const float*)d_in[17];
    float* out = (float*)d_out;

    // workspace layout (bytes; peak 104 MB, proven available)
    char* w = (char*)d_ws;
    short* wqt = (short*)(w + (size_t)0);
    short* wkt = (short*)(w + ((size_t)2  << 20));
    short* wvt = (short*)(w + ((size_t)4  << 20));
    short* wot = (short*)(w + ((size_t)6  << 20));
    short* w1t = (short*)(w + ((size_t)8  << 20));
    short* w2t = (short*)(w + ((size_t)16 << 20));
    short* hb  = (short*)(w + ((size_t)24 << 20));   // LN1 out, later LN2 out
    short* qb  = (short*)(w + ((size_t)40 << 20));
    short* kbf = (short*)(w + ((size_t)56 << 20));
    short* attnb = (short*)(w + ((size_t)72 << 20));
    short* vtb = (short*)(w + ((size_t)88 << 20));
    short* ffb = qb;   // q/k/vt dead by MLP1 (64 MB span 40..104)

    dim3 blk(256);

    // weight prep: W [K,N] fp32 -> W^T [N,K] bf16
    transpose_cast<<<dim3(32, 32),  blk, 0, stream>>>(wq, wqt, 1024, 1024);
    transpose_cast<<<dim3(32, 32),  blk, 0, stream>>>(wk, wkt, 1024, 1024);
    transpose_cast<<<dim3(32, 32),  blk, 0, stream>>>(wv, wvt, 1024, 1024);
    transpose_cast<<<dim3(32, 32),  blk, 0, stream>>>(wo, wot, 1024, 1024);
    transpose_cast<<<dim3(128, 32), blk, 0, stream>>>(w1, w1t, 1024, 4096);
    transpose_cast<<<dim3(32, 128), blk, 0, stream>>>(w2, w2t, 4096, 1024);

    // 1) h = LN1(x) -> bf16
    ln_kernel<<<N_TOK, blk, 0, stream>>>(x, ln1s, ln1b, hb);

    // 2) q/k/v GEMMs; V writes directly in transposed attention layout
    dim3 g1(D_MODEL / 128, N_TOK / 128);
    gemm_bf16<<<g1, blk, 0, stream>>>(hb, 1024, wqt, 1024, bq, nullptr,
                                      nullptr, qb, nullptr, 1024, 1024, 0);
    gemm_bf16<<<g1, blk, 0, stream>>>(hb, 1024, wkt, 1024, bk, nullptr,
                                      nullptr, kbf, nullptr, 1024, 1024, 0);
    gemm_bf16<<<g1, blk, 0, stream>>>(hb, 1024, wvt, 1024, bv, nullptr,
                                      nullptr, nullptr, vtb, 1024, 1024, 0);

    // 3) flash attention -> attnb (bf16)
    attn_kernel<<<dim3(16, 16, 8), blk, 0, stream>>>(qb, kbf, vtb, amask, attnb);

    // 4) out = x + attn @ wo + bo  (fp32 out)
    gemm_bf16<<<g1, blk, 0, stream>>>(attnb, 1024, wot, 1024, bo, x,
                                      out, nullptr, nullptr, 1024, 1024, 0);

    // 5) h = LN2(out) -> bf16
    ln_kernel<<<N_TOK, blk, 0, stream>>>(out, ln2s, ln2b, hb);

    // 6) MLP
    gemm_bf16<<<dim3(FF_DIM / 128, N_TOK / 128), blk, 0, stream>>>(
        hb, 1024, w1t, 1024, b1, nullptr, nullptr, ffb, nullptr, 4096, 1024, 1);
    gemm_bf16<<<dim3(D_MODEL / 128, N_TOK / 128), blk, 0, stream>>>(
        ffb, 4096, w2t, 4096, b2, out, out, nullptr, nullptr, 1024, 4096, 0);
}

// Round 4
// 767.708 us; speedup vs baseline: 5.7981x; 1.0276x over previous
//
#include <hip/hip_runtime.h>
#include <math.h>

#define D_MODEL 1024
#define N_TOK   8192
#define SEQ_L   1024
#define N_HEAD  16
#define HEAD_D  64
#define FF_DIM  4096

typedef __attribute__((ext_vector_type(8))) short bf16x8;   // 8 bf16 = 4 VGPRs
typedef __attribute__((ext_vector_type(4))) short short4v;
typedef __attribute__((ext_vector_type(4))) float f32x4;

#define MFMA16(a, b, c) __builtin_amdgcn_mfma_f32_16x16x32_bf16((a), (b), (c), 0, 0, 0)

// async global->LDS, 16B per lane; LDS dest = wave-uniform base + lane*16
#define GLD16(gp, lp) __builtin_amdgcn_global_load_lds(                      \
    (const __attribute__((address_space(1))) void*)(gp),                     \
    (__attribute__((address_space(3))) void*)(lp), 16, 0, 0)

__device__ __forceinline__ short f2bf(float f) {   // fp32 -> bf16 (RNE)
    unsigned u = __float_as_uint(f);
    u += 0x7fffu + ((u >> 16) & 1u);
    return (short)(u >> 16);
}

// ---------------------------------------------------------------------------
// LayerNorm fp32 -> bf16. One block (256 thr) per token.
// ---------------------------------------------------------------------------
__global__ __launch_bounds__(256) void ln_kernel(const float* __restrict__ x,
                                                 const float* __restrict__ g,
                                                 const float* __restrict__ b,
                                                 short* __restrict__ o)
{
    int t = blockIdx.x;
    const float* xr = x + (size_t)t * D_MODEL;
    short* orow = o + (size_t)t * D_MODEL;
    float vals[4];
    float lsum = 0.f, lsq = 0.f;
#pragma unroll
    for (int i = 0; i < 4; i++) {
        float v = xr[threadIdx.x + i * 256];
        vals[i] = v; lsum += v; lsq += v * v;
    }
#pragma unroll
    for (int off = 32; off > 0; off >>= 1) {
        lsum += __shfl_down(lsum, off);
        lsq  += __shfl_down(lsq,  off);
    }
    __shared__ float red[8];
    int wid = threadIdx.x >> 6, lane = threadIdx.x & 63;
    if (lane == 0) { red[wid] = lsum; red[4 + wid] = lsq; }
    __syncthreads();
    if (threadIdx.x == 0) {
        red[0] = red[0] + red[1] + red[2] + red[3];
        red[4] = red[4] + red[5] + red[6] + red[7];
    }
    __syncthreads();
    float mean = red[0] * (1.f / D_MODEL);
    float var  = red[4] * (1.f / D_MODEL) - mean * mean;
    float inv  = rsqrtf(var + 1e-5f);
#pragma unroll
    for (int i = 0; i < 4; i++) {
        int c = threadIdx.x + i * 256;
        orow[c] = f2bf((vals[i] - mean) * inv * g[c] + b[c]);
    }
}

// ---------------------------------------------------------------------------
// Transpose + cast: src fp32 [R,C] -> dst bf16 [C,R]. 32x32 tiles.
// ---------------------------------------------------------------------------
__global__ __launch_bounds__(256) void transpose_cast(const float* __restrict__ src,
                                                      short* __restrict__ dst,
                                                      int R, int C)
{
    __shared__ float t[32][33];
    int r0 = blockIdx.y * 32, c0 = blockIdx.x * 32;
    int tid = threadIdx.x;
#pragma unroll
    for (int i = 0; i < 4; i++) {
        int idx = i * 256 + tid;
        int r = idx >> 5, c = idx & 31;
        t[r][c] = src[(size_t)(r0 + r) * C + c0 + c];
    }
    __syncthreads();
#pragma unroll
    for (int i = 0; i < 4; i++) {
        int idx = i * 256 + tid;
        int rr = idx >> 5, cc = idx & 31;
        dst[(size_t)(c0 + rr) * R + r0 + cc] = f2bf(t[cc][rr]);
    }
}

// ---------------------------------------------------------------------------
// bf16 MFMA GEMM (m97 structure): C[M,N] = epilogue(A[M,K] @ Bt[N,K]^T)
// 128x128 tile, BK=32, 256 thr = 4 waves, each wave 64x64 via 4x4 16x16 frags.
// C/D layout: col=lane&15, row=quad*4+reg.
// Modes:
//   qkv=1: N=3072 fused QKV. col>>10 selects segment: 0/1 -> bf16 store to
//          Cb + seg*8M (qb,kbf contiguous at 16MB stride), 2 -> transposed
//          V store to Cvt ([(b*H+h)*64+d][SEQ_L]); bias from bias/bias2/bias3.
//   else:  +bias, optional quick_gelu, optional fp32 resid, store Cf or Cb.
// ---------------------------------------------------------------------------
__global__ __launch_bounds__(256) void gemm_bf16(
    const short* __restrict__ A, int lda,
    const short* __restrict__ Bt, int ldb,
    const float* __restrict__ bias,
    const float* __restrict__ bias2,
    const float* __restrict__ bias3,
    const float* __restrict__ resid,
    float* __restrict__ Cf, short* __restrict__ Cb, short* __restrict__ Cvt,
    int ldc, int K, int act, int qkv)
{
    __shared__ __align__(16) short sA[128 * 32];
    __shared__ __align__(16) short sB[128 * 32];
    const int tid = threadIdx.x;
    const int lane = tid & 63, wave = tid >> 6;
    const int quad = lane >> 4, l15 = lane & 15;
    const int bm = blockIdx.y * 128, bn = blockIdx.x * 128;
    const int wm = (wave >> 1) * 64, wn = (wave & 1) * 64;

    const int ca = tid, cb = tid + 256;
    const int ra = ca >> 2, ka = (ca & 3) << 3;
    const int rb = cb >> 2, kb = (cb & 3) << 3;

    f32x4 acc[4][4];
#pragma unroll
    for (int i = 0; i < 4; i++)
#pragma unroll
        for (int j = 0; j < 4; j++) acc[i][j] = (f32x4){0.f, 0.f, 0.f, 0.f};

    for (int k0 = 0; k0 < K; k0 += 32) {
        __syncthreads();
        GLD16(A  + (size_t)(bm + ra) * lda + k0 + ka, &sA[ca * 8]);
        GLD16(A  + (size_t)(bm + rb) * lda + k0 + kb, &sA[cb * 8]);
        GLD16(Bt + (size_t)(bn + ra) * ldb + k0 + ka, &sB[ca * 8]);
        GLD16(Bt + (size_t)(bn + rb) * ldb + k0 + kb, &sB[cb * 8]);
        __syncthreads();
        bf16x8 af[4], bfr[4];
#pragma unroll
        for (int mt = 0; mt < 4; mt++)
            af[mt] = *(const bf16x8*)&sA[(wm + mt * 16 + l15) * 32 + quad * 8];
#pragma unroll
        for (int nt = 0; nt < 4; nt++)
            bfr[nt] = *(const bf16x8*)&sB[(wn + nt * 16 + l15) * 32 + quad * 8];
#pragma unroll
        for (int mt = 0; mt < 4; mt++)
#pragma unroll
            for (int nt = 0; nt < 4; nt++)
                acc[mt][nt] = MFMA16(af[mt], bfr[nt], acc[mt][nt]);
    }

#pragma unroll
    for (int mt = 0; mt < 4; mt++)
#pragma unroll
        for (int nt = 0; nt < 4; nt++) {
            int row0 = bm + wm + mt * 16 + quad * 4;
            int col  = bn + wn + nt * 16 + l15;
            if (qkv) {
                int seg = col >> 10, cloc = col & 1023;
                const float* bp = (seg == 0) ? bias : (seg == 1) ? bias2 : bias3;
                float bval = bp[cloc];
                if (seg == 2) {
                    // V transposed store: page=(b*H+h)*64+d, index = seq pos
                    int bb = row0 >> 10, l0 = row0 & 1023;
                    size_t page = (size_t)(bb * N_HEAD + (cloc >> 6)) * HEAD_D + (cloc & 63);
                    short4v pk = { f2bf(acc[mt][nt][0] + bval), f2bf(acc[mt][nt][1] + bval),
                                   f2bf(acc[mt][nt][2] + bval), f2bf(acc[mt][nt][3] + bval) };
                    *(short4v*)&Cvt[page * SEQ_L + l0] = pk;
                } else {
                    short* dst = Cb + (size_t)seg * ((size_t)N_TOK * D_MODEL);
#pragma unroll
                    for (int r = 0; r < 4; r++)
                        dst[(size_t)(row0 + r) * D_MODEL + cloc] = f2bf(acc[mt][nt][r] + bval);
                }
            } else {
#pragma unroll
                for (int r = 0; r < 4; r++) {
                    int row = row0 + r;
                    float v = acc[mt][nt][r] + bias[col];
                    if (act) v = v / (1.f + __expf(-1.702f * v));   // quick_gelu
                    if (resid) v += resid[(size_t)row * ldc + col];
                    if (Cb) Cb[(size_t)row * ldc + col] = f2bf(v);
                    else    Cf[(size_t)row * ldc + col] = v;
                }
            }
        }
}

// ---------------------------------------------------------------------------
// Flash attention, bf16 MFMA, S^T formulation: S^T = K·Q^T so the C-layout
// column (lane&15) is the q-row -> softmax max/sum are IN-REGISTER over the
// lane's 16 scores + 2 shuffles (xor16/32 across quads). m/l are per-lane
// scalars. P packs to pslab[q][key] with ds_write_b64. Per-wave private;
// no block barriers in the K-loop. 1-D grid with XCD-aware swizzle: each
// XCD owns 16 (b,h) pairs so K/V pages live in one XCD's L2.
// ---------------------------------------------------------------------------
__global__ __launch_bounds__(256) void attn_kernel(
    const short* __restrict__ Q, const short* __restrict__ Kb,
    const short* __restrict__ Vt, const int* __restrict__ mask,
    short* __restrict__ O)
{
    __shared__ __align__(16) float sMB[SEQ_L];
    __shared__ __align__(16) short sP[64 * 72];   // [q][key] rows 144B
    __shared__ __align__(16) float sAl[4][20];    // per-wave alpha broadcast

    const int g = blockIdx.x;
    const int xcd = g & 7, slot = g >> 3;
    const int qt = slot & 15, bhl = slot >> 4;
    const int bh = xcd * 16 + bhl;
    const int b = bh >> 4, h = bh & 15;

    const int tid = threadIdx.x;
    const int wave = tid >> 6, lane = tid & 63;
    const int quad = lane >> 4, l15 = lane & 15;

    for (int i = tid; i < SEQ_L; i += 256)
        sMB[i] = (mask[b * SEQ_L + i] > 0) ? 0.f : -1e30f;
    __syncthreads();

    const int qbase = b * SEQ_L + qt * 64;
    const short* qp = Q + (size_t)(qbase + wave * 16 + l15) * D_MODEL + h * HEAD_D + quad * 8;
    bf16x8 qf0 = *(const bf16x8*)qp;
    bf16x8 qf1 = *(const bf16x8*)(qp + 32);

    f32x4 o4[4];
#pragma unroll
    for (int nt = 0; nt < 4; nt++) o4[nt] = (f32x4){0.f, 0.f, 0.f, 0.f};
    float mrow = -1e30f, lrow = 0.f;     // per-lane: q = l15 of this wave
    const size_t vpage = (size_t)(b * N_HEAD + h) * HEAD_D * SEQ_L;
    short* pslab = &sP[wave * 16 * 72];  // per-wave private [16 q][72]

#pragma unroll 2
    for (int kt = 0; kt < SEQ_L / 64; kt++) {
        const int kbase = b * SEQ_L + kt * 64;
        // issue ALL K and V loads up front
        bf16x8 kf[4][2], vf[4][2];
#pragma unroll
        for (int nt = 0; nt < 4; nt++) {
            const short* kp = Kb + (size_t)(kbase + nt * 16 + l15) * D_MODEL + h * HEAD_D + quad * 8;
            kf[nt][0] = *(const bf16x8*)kp;
            kf[nt][1] = *(const bf16x8*)(kp + 32);
            const short* vp = Vt + vpage + (size_t)(nt * 16 + l15) * SEQ_L + kt * 64 + quad * 8;
            vf[nt][0] = *(const bf16x8*)vp;
            vf[nt][1] = *(const bf16x8*)(vp + 32);
        }
        // S^T tiles: D[m=key][n=q], key = nt*16 + quad*4 + r, q = l15
        f32x4 s[4];
#pragma unroll
        for (int nt = 0; nt < 4; nt++) s[nt] = (f32x4){0.f, 0.f, 0.f, 0.f};
#pragma unroll
        for (int nt = 0; nt < 4; nt++) {
            s[nt] = MFMA16(kf[nt][0], qf0, s[nt]);
            s[nt] = MFMA16(kf[nt][1], qf1, s[nt]);
        }
        // scale + mask (mask indexed by key = row)
#pragma unroll
        for (int nt = 0; nt < 4; nt++) {
            f32x4 mb = *(const f32x4*)&sMB[kt * 64 + nt * 16 + quad * 4];
#pragma unroll
            for (int r = 0; r < 4; r++) s[nt][r] = s[nt][r] * 0.125f + mb[r];
        }
        // in-register max over this lane's 16 scores, then 2 shuffles
        float pmax = s[0][0];
#pragma unroll
        for (int nt = 0; nt < 4; nt++)
#pragma unroll
            for (int r = 0; r < 4; r++) pmax = fmaxf(pmax, s[nt][r]);
        pmax = fmaxf(pmax, __shfl_xor(pmax, 16));
        pmax = fmaxf(pmax, __shfl_xor(pmax, 32));
        float mnew = fmaxf(mrow, pmax);
        float alpha = __expf(mrow - mnew);
        mrow = mnew;

        float ls = 0.f;
#pragma unroll
        for (int nt = 0; nt < 4; nt++) {
            float p0_ = __expf(s[nt][0] - mnew);
            float p1_ = __expf(s[nt][1] - mnew);
            float p2_ = __expf(s[nt][2] - mnew);
            float p3_ = __expf(s[nt][3] - mnew);
            ls += (p0_ + p1_) + (p2_ + p3_);
            short4v pk = { f2bf(p0_), f2bf(p1_), f2bf(p2_), f2bf(p3_) };
            *(short4v*)&pslab[l15 * 72 + nt * 16 + quad * 4] = pk;
        }
        ls += __shfl_xor(ls, 16);
        ls += __shfl_xor(ls, 32);
        lrow = lrow * alpha + ls;

        // broadcast alpha to O-accumulator rows (row = q = quad*4+r there)
        if (quad == 0) sAl[wave][l15] = alpha;
        f32x4 av = *(const f32x4*)&sAl[wave][quad * 4];
#pragma unroll
        for (int nt = 0; nt < 4; nt++)
#pragma unroll
            for (int r = 0; r < 4; r++) o4[nt][r] *= av[r];

        // P A-frag [m=q=l15][k=key=quad*8+j] straight from the packed slab
        const short* pp = &pslab[l15 * 72 + quad * 8];
        bf16x8 p0 = *(const bf16x8*)pp;
        bf16x8 p1 = *(const bf16x8*)(pp + 32);
#pragma unroll
        for (int nt = 0; nt < 4; nt++) {
            o4[nt] = MFMA16(p0, vf[nt][0], o4[nt]);
            o4[nt] = MFMA16(p1, vf[nt][1], o4[nt]);
        }
    }
    // final 1/l broadcast to O rows
    if (quad == 0) sAl[wave][l15] = 1.f / lrow;
    f32x4 iv = *(const f32x4*)&sAl[wave][quad * 4];
#pragma unroll
    for (int nt = 0; nt < 4; nt++)
#pragma unroll
        for (int r = 0; r < 4; r++)
            O[(size_t)(qbase + wave * 16 + quad * 4 + r) * D_MODEL
              + h * HEAD_D + nt * 16 + l15] = f2bf(o4[nt][r] * iv[r]);
}

// ---------------------------------------------------------------------------
// Launch
// ---------------------------------------------------------------------------
extern "C" void kernel_launch(void* const* d_in, const int* in_sizes, int n_in,
                              void* d_out, int out_size, void* d_ws, size_t ws_size,
                              hipStream_t stream)
{
    const float* x     = (const float*)d_in[0];
    const int*   amask = (const int*)  d_in[1];
    const float* wq    = (const float*)d_in[2];
    const float* bq    = (const float*)d_in[3];
    const float* wk    = (const float*)d_in[4];
    const float* bk    = (const float*)d_in[5];
    const float* wv    = (const float*)d_in[6];
    const float* bv    = (const float*)d_in[7];
    const float* wo    = (const float*)d_in[8];
    const float* bo    = (const float*)d_in[9];
    const float* ln1s  = (const float*)d_in[10];
    const float* ln1b  = (const float*)d_in[11];
    const float* ln2s  = (const float*)d_in[12];
    const float* ln2b  = (const float*)d_in[13];
    const float* w1    = (const float*)d_in[14];
    const float* b1    = (const float*)d_in[15];
    const float* w2    = (const float*)d_in[16];
    const float* b2    = (const float*)d_in[17];
    float* out = (float*)d_out;

    // workspace layout (bytes; peak 104 MB, proven available in R2/R3)
    char* w = (char*)d_ws;
    short* wqkvt = (short*)(w + (size_t)0);          // [3072][1024] bf16, 6MB
    short* wot   = (short*)(w + ((size_t)6  << 20));
    short* w1t   = (short*)(w + ((size_t)8  << 20));
    short* w2t   = (short*)(w + ((size_t)16 << 20));
    short* hb    = (short*)(w + ((size_t)24 << 20)); // LN1 out, later LN2 out
    short* qb    = (short*)(w + ((size_t)40 << 20)); // qb,kbf contiguous:
    short* kbf   = (short*)(w + ((size_t)56 << 20)); //   16MB stride for qkv mode
    short* attnb = (short*)(w + ((size_t)72 << 20));
    short* vtb   = (short*)(w + ((size_t)88 << 20));
    short* ffb   = qb;   // q/k/vt dead by MLP1 (64 MB span 40..104)

    dim3 blk(256);

    // weight prep: W [K,N] fp32 -> W^T [N,K] bf16 (QKV stacked into one)
    transpose_cast<<<dim3(32, 32),  blk, 0, stream>>>(wq, wqkvt,              1024, 1024);
    transpose_cast<<<dim3(32, 32),  blk, 0, stream>>>(wk, wqkvt + 1024 * 1024, 1024, 1024);
    transpose_cast<<<dim3(32, 32),  blk, 0, stream>>>(wv, wqkvt + 2048 * 1024, 1024, 1024);
    transpose_cast<<<dim3(32, 32),  blk, 0, stream>>>(wo, wot, 1024, 1024);
    transpose_cast<<<dim3(128, 32), blk, 0, stream>>>(w1, w1t, 1024, 4096);
    transpose_cast<<<dim3(32, 128), blk, 0, stream>>>(w2, w2t, 4096, 1024);

    // 1) h = LN1(x) -> bf16
    ln_kernel<<<N_TOK, blk, 0, stream>>>(x, ln1s, ln1b, hb);

    // 2) fused QKV GEMM: writes qb, kbf, and V directly transposed (vtb)
    gemm_bf16<<<dim3(3 * D_MODEL / 128, N_TOK / 128), blk, 0, stream>>>(
        hb, 1024, wqkvt, 1024, bq, bk, bv, nullptr,
        nullptr, qb, vtb, 1024, 1024, 0, 1);

    // 3) flash attention -> attnb (bf16); 1-D grid, XCD swizzle inside
    attn_kernel<<<dim3(2048), blk, 0, stream>>>(qb, kbf, vtb, amask, attnb);

    // 4) out = x + attn @ wo + bo  (fp32 out)
    gemm_bf16<<<dim3(D_MODEL / 128, N_TOK / 128), blk, 0, stream>>>(
        attnb, 1024, wot, 1024, bo, nullptr, nullptr, x,
        out, nullptr, nullptr, 1024, 1024, 0, 0);

    // 5) h = LN2(out) -> bf16
    ln_kernel<<<N_TOK, blk, 0, stream>>>(out, ln2s, ln2b, hb);

    // 6) MLP
    gemm_bf16<<<dim3(FF_DIM / 128, N_TOK / 128), blk, 0, stream>>>(
        hb, 1024, w1t, 1024, b1, nullptr, nullptr, nullptr,
        nullptr, ffb, nullptr, 4096, 1024, 1, 0);
    gemm_bf16<<<dim3(D_MODEL / 128, N_TOK / 128), blk, 0, stream>>>(
        ffb, 4096, w2t, 4096, b2, nullptr, nullptr, out,
        out, nullptr, nullptr, 1024, 4096, 0, 0);
}